// Round 14
// baseline (267.816 us; speedup 1.0000x reference)
//
#include <hip/hip_runtime.h>
#include <cstdint>
#include <cstddef>

#define NNODES 50000
#define NEDGES 800000
#define INDIM  256
#define HD     128   // H*D
#define NH     4
#define NEG    0.2f
#define LOG2E  1.44269504088896340736f

#define SCAN_B ((NNODES + 255) / 256)   // 196 blocks

// fusedPre partition (clear cnt | conv_w)
#define CLR_BLKS   49                               // 12544 int4 slots >= 12500
#define CONVW_BLKS 64
// fusedG block partition (gemm 128x256 | hist 8 edges/thread)
#define GEMM_BLKS  ((NNODES + 127) / 128)           // 391
#define HIST_BLKS  ((NEDGES + 2047) / 2048)         // 391
// scatter standalone
#define SCAT_BLKS  ((NEDGES + 2047) / 2048)         // 391

typedef __attribute__((ext_vector_type(8))) short   short8;   // 8 bf16 (4 VGPRs)
typedef __attribute__((ext_vector_type(8))) ushort  ushort8;
typedef __attribute__((ext_vector_type(4))) float   floatx4;

// fast hardware exp2: single v_exp_f32 (exp2f() is the libm-accurate path and
// cost +8 VGPR / +18% VALU cycles in r12 -- do not use it here)
#define EXP2(x) __builtin_amdgcn_exp2f(x)

// f32 -> bf16 (round-to-nearest-even), raw bits
__device__ __forceinline__ ushort f2bf(float f) {
    unsigned u = __float_as_uint(f);
    unsigned r = u + 0x7fffu + ((u >> 16) & 1u);
    return (ushort)(r >> 16);
}
__device__ __forceinline__ float bf2f(ushort u) {
    return __uint_as_float(((unsigned)u) << 16);
}

// LDS chunk swizzle: conflict-free staging writes + fragment reads
__device__ __forceinline__ int swz(int c) { return c ^ ((c >> 4) & 7); }

// ================= fusedPre: clear cnt | W convert+transpose =================
__global__ __launch_bounds__(256) void fusedPre_kernel(
        int* __restrict__ cnt_work,
        const float* __restrict__ Wsrc, const float* __restrict__ Wdst,
        ushort* __restrict__ Wt) {
    __shared__ float t[32][33];
    const int bid = blockIdx.x;
    const int tid = threadIdx.x;

    if (bid < CLR_BLKS) {
        int i = bid * 256 + tid;
        if (i < (NNODES + 3) / 4)
            ((int4*)cnt_work)[i] = make_int4(0, 0, 0, 0);
        return;
    }
    // ---- W convert+transpose (LDS-tiled): Wt[n][k] bf16 ----
    int wb = bid - CLR_BLKS;                      // 0..63
    int kb = (wb & 7) * 32, nb = (wb >> 3) * 32;
    int tx = tid & 31, ty = tid >> 5;
    for (int i = ty; i < 32; i += 8) {
        int k = kb + i, n = nb + tx;
        float v = (n < HD) ? Wsrc[(size_t)k * HD + n] : Wdst[(size_t)k * HD + (n - HD)];
        t[i][tx] = v;
    }
    __syncthreads();
    for (int i = ty; i < 32; i += 8) {
        int n = nb + i, k = kb + tx;
        Wt[(size_t)n * INDIM + k] = f2bf(t[tx][i]);
    }
}

// ================= fusedG: MFMA GEMM (128x256, f32 A direct) | hist =================
// GEMM needs only convw+h (ready after fusedPre); hist needs only cleared cnt.
// Both independent -> overlap: GEMM's ~25us hides under hist's ~65us atomic pass.
// The scatter is NOT here anymore: standalone scatter gets full occupancy for its
// returning-atomic chains (it was strangled at ~14% occupancy by the GEMM's
// LDS/launch-bounds profile -- r13 counters).
__global__ __launch_bounds__(256, 2) void fusedG_kernel(
        const float* __restrict__ h, const ushort* __restrict__ Wt,
        const float* __restrict__ bsrc, const float* __restrict__ bdst,
        ushort* __restrict__ el_bf, float* __restrict__ er,
        const int* __restrict__ dst, int* __restrict__ cnt_work) {
    __shared__ ushort As[512 * 8];    // 128 rows x 32 k bf16 (8 KB)
    __shared__ ushort Bs[1024 * 8];   // 256 cols x 32 k bf16 (16 KB)

    const int bid = blockIdx.x;
    const int tid = threadIdx.x;

    if (bid >= GEMM_BLKS) {
        // ---- hist: 8 edges/thread (stride-256, coalesced), non-returning atomics ----
        int base = (bid - GEMM_BLKS) * 2048 + tid;
        int dd[8];
#pragma unroll
        for (int k = 0; k < 8; ++k) {
            int e = base + k * 256;
            dd[k] = (e < NEDGES) ? dst[e] : -1;
        }
#pragma unroll
        for (int k = 0; k < 8; ++k) {
            if (dd[k] >= 0) atomicAdd(cnt_work + dd[k], 1);
        }
        return;
    }

    const int wave = tid >> 6, lane = tid & 63;
    const int row0 = bid * 128;
    const int l15  = lane & 15, quad = lane >> 4;

    floatx4 acc[2][16];
#pragma unroll
    for (int i = 0; i < 2; ++i)
#pragma unroll
        for (int j = 0; j < 16; ++j) acc[i][j] = (floatx4){0.f, 0.f, 0.f, 0.f};

    for (int kk = 0; kk < INDIM; kk += 32) {
        // ---- A staging: 512 chunks of 8, f32 source + convert ----
#pragma unroll
        for (int it = 0; it < 2; ++it) {
            int idx = tid + it * 256;    // 0..511
            int r = idx >> 2;            // 0..127 (row)
            int kq = idx & 3;            // k-quad (8 elems)
            int c = (r >> 4) * 64 + kq * 16 + (r & 15);
            int grow = row0 + r;
            ushort8 aw = (ushort8){0,0,0,0,0,0,0,0};
            if (grow < NNODES) {
                const float* p = h + (size_t)grow * INDIM + kk + kq * 8;
                float4 v0 = *(const float4*)p;
                float4 v1 = *(const float4*)(p + 4);
                aw[0] = f2bf(v0.x); aw[1] = f2bf(v0.y); aw[2] = f2bf(v0.z); aw[3] = f2bf(v0.w);
                aw[4] = f2bf(v1.x); aw[5] = f2bf(v1.y); aw[6] = f2bf(v1.z); aw[7] = f2bf(v1.w);
            }
            *(ushort8*)(As + swz(c) * 8) = aw;
        }
        // ---- B staging: 1024 chunks of 8 (256 cols) ----
#pragma unroll
        for (int it = 0; it < 4; ++it) {
            int idx = tid + it * 256;    // 0..1023
            int r = idx >> 2;            // 0..255 (col)
            int kq = idx & 3;
            int c = (r >> 4) * 64 + kq * 16 + (r & 15);   // 0..1023
            ushort8 bw = *(const ushort8*)(Wt + (size_t)r * INDIM + kk + kq * 8);
            *(ushort8*)(Bs + swz(c) * 8) = bw;
        }
        __syncthreads();

        short8 af[2];
#pragma unroll
        for (int tm = 0; tm < 2; ++tm) {
            int c = (wave * 2 + tm) * 64 + quad * 16 + l15;
            af[tm] = *(const short8*)(As + swz(c) * 8);
        }
#pragma unroll
        for (int tn = 0; tn < 16; ++tn) {
            int c = tn * 64 + quad * 16 + l15;
            short8 bfr = *(const short8*)(Bs + swz(c) * 8);
            acc[0][tn] = __builtin_amdgcn_mfma_f32_16x16x32_bf16(af[0], bfr, acc[0][tn], 0, 0, 0);
            acc[1][tn] = __builtin_amdgcn_mfma_f32_16x16x32_bf16(af[1], bfr, acc[1][tn], 0, 0, 0);
        }
        __syncthreads();
    }

    // epilogue: C/D layout col=lane&15, row=quad*4+reg
#pragma unroll
    for (int tn = 0; tn < 8; ++tn) {
        int col = tn * 16 + l15;              // 0..127 -> el
        float bias = bsrc[col];
#pragma unroll
        for (int tm = 0; tm < 2; ++tm)
#pragma unroll
            for (int reg = 0; reg < 4; ++reg) {
                int row = row0 + wave * 32 + tm * 16 + quad * 4 + reg;
                if (row < NNODES)
                    el_bf[(size_t)row * HD + col] = f2bf(acc[tm][tn][reg] + bias);
            }
    }
#pragma unroll
    for (int tn = 8; tn < 16; ++tn) {
        int col = tn * 16 + l15 - HD;         // 0..127 -> er
        float bias = bdst[col];
#pragma unroll
        for (int tm = 0; tm < 2; ++tm)
#pragma unroll
            for (int reg = 0; reg < 4; ++reg) {
                int row = row0 + wave * 32 + tm * 16 + quad * 4 + reg;
                if (row < NNODES)
                    er[(size_t)row * HD + col] = acc[tm][tn][reg] + bias;
            }
    }
}

// ================= CSR scan: 2-kernel chain =================
__global__ __launch_bounds__(256) void scan_partial_kernel(
        const int* __restrict__ cnt, int* __restrict__ partials) {
    __shared__ int lds[256];
    int i = blockIdx.x * 256 + threadIdx.x;
    lds[threadIdx.x] = (i < NNODES) ? cnt[i] : 0;
    __syncthreads();
    for (int off = 128; off > 0; off >>= 1) {
        if (threadIdx.x < off) lds[threadIdx.x] += lds[threadIdx.x + off];
        __syncthreads();
    }
    if (threadIdx.x == 0) partials[blockIdx.x] = lds[0];
}

__global__ __launch_bounds__(256) void scan_final_kernel(
        int* __restrict__ cnt_work, const int* __restrict__ partials,
        int* __restrict__ rowptr) {
    __shared__ int lds[256];
    __shared__ int sh_prefix;
    const int t = threadIdx.x;
    const int bid = blockIdx.x;

    // prefix = sum of partials[0..bid-1]  (bid <= 195 < 256)
    int pv = (t < bid) ? partials[t] : 0;
    lds[t] = pv;
    __syncthreads();
    for (int off = 128; off > 0; off >>= 1) {
        if (t < off) lds[t] += lds[t + off];
        __syncthreads();
    }
    if (t == 0) sh_prefix = lds[0];
    __syncthreads();
    const int prefix = sh_prefix;
    __syncthreads();                       // lds reuse barrier

    const int i = bid * 256 + t;
    int v = (i < NNODES) ? cnt_work[i] : 0;
    lds[t] = v;
    __syncthreads();
    for (int off = 1; off < 256; off <<= 1) {
        int u = (t >= off) ? lds[t - off] : 0;
        __syncthreads();
        lds[t] += u;
        __syncthreads();
    }
    if (i < NNODES) {
        int start = prefix + lds[t] - v;   // exclusive + global prefix
        rowptr[i] = start;
        cnt_work[i] = start;               // scatter cursor
    }
    if (bid == SCAN_B - 1 && t == 255) rowptr[NNODES] = prefix + lds[255];
}

// ================= scatter: standalone, full occupancy =================
// 8 edges/thread, returning atomics on cnt_work cursors, packed int2 stores into
// the dense CSR epair region. No LDS, no launch-bounds cap: 32 waves/CU of 8-deep
// atomic chains (was ~14% occupancy inside fusedB -- r13 counters).
__global__ __launch_bounds__(256) void scatter_kernel(
        const int* __restrict__ src, const int* __restrict__ dst,
        int* __restrict__ cnt_work, int2* __restrict__ epair) {
    int base = blockIdx.x * 2048 + threadIdx.x;
    int ss[8], dd[8], pos[8];
#pragma unroll
    for (int k = 0; k < 8; ++k) {
        int e = base + k * 256;
        if (e < NEDGES) { ss[k] = src[e]; dd[k] = dst[e]; } else dd[k] = -1;
    }
#pragma unroll
    for (int k = 0; k < 8; ++k) {
        if (dd[k] >= 0) pos[k] = atomicAdd(cnt_work + dd[k], 1);
    }
#pragma unroll
    for (int k = 0; k < 8; ++k) {
        int e = base + k * 256;
        if (dd[k] >= 0) epair[pos[k]] = make_int2(e, ss[k]);
    }
}

// ================= node_fused: r5-proven branchless body + exp2 rebasing (HW exp2) ==
// one wave per node; lane l owns dims 2l,2l+1; head hh = l>>4. CSR int2 epair.
// a0,a1 pre-scaled by log2(e) -> scores in log2 domain; EXP2 = raw v_exp_f32
// builtin (single instruction). Body shape is the proven form -- do NOT
// restructure (batched rewrites, defer-max, buckets all regressed).
#define DEGCAP 128

__global__ __launch_bounds__(256) void node_fused_kernel(
        const ushort* __restrict__ el_bf, const float* __restrict__ er,
        const int* __restrict__ rowptr, const int2* __restrict__ epair,
        const float* __restrict__ attn,
        float* __restrict__ out_feat, float* __restrict__ out_a) {
    __shared__ float sp[4][DEGCAP * NH];   // 2 KB per wave

    const int wv = threadIdx.x >> 6;
    const int n = blockIdx.x * 4 + wv;
    if (n >= NNODES) return;
    const int lane = threadIdx.x & 63;
    const int hh = lane >> 4;
    const int lo = rowptr[n], hi = rowptr[n + 1];
    const int deg = hi - lo;
    float* spw = sp[wv];
    const int l2 = lane * 2;

    const float2 rv = *(const float2*)(er + (size_t)n * HD + l2);
    const float a0 = attn[l2] * LOG2E, a1 = attn[l2 + 1] * LOG2E;

    float m = -3.4e38f, lsum = 0.0f, acc0 = 0.0f, acc1 = 0.0f;

    if (deg > 0 && deg <= DEGCAP) {
        // preload first chunk of up to 16 edge-source indices (coalesced, clamped)
        int jj0 = (lane & 15);
        if (jj0 >= deg) jj0 = deg - 1;
        int si = epair[lo + jj0].y;

        for (int base = 0; base < deg; base += 16) {
            // issue all gathers of this chunk (wave-uniform scalar base per edge)
            ushort2 u[16];
#pragma unroll
            for (int j = 0; j < 16; ++j) {
                if (base + j < deg) {
                    int s = __builtin_amdgcn_readlane(si, j);
                    u[j] = *(const ushort2*)(el_bf + (size_t)s * HD + l2);
                }
            }
            // prefetch next chunk's indices (hides index-load latency under compute)
            int si_nxt = si;
            if (base + 16 < deg) {
                int jj = base + 16 + (lane & 15);
                if (jj >= deg) jj = deg - 1;
                si_nxt = epair[lo + jj].y;
            }
            // process chunk: per-edge, branchless online softmax (proven shape)
#pragma unroll
            for (int j = 0; j < 16; ++j) {
                if (base + j < deg) {
                    float evx = bf2f(u[j].x), evy = bf2f(u[j].y);
                    float x0 = evx + rv.x; x0 = fmaxf(x0, NEG * x0);
                    float x1 = evy + rv.y; x1 = fmaxf(x1, NEG * x1);
                    float p = x0 * a0 + x1 * a1;        // log2-domain score
                    p += __shfl_xor(p, 1, 16);
                    p += __shfl_xor(p, 2, 16);
                    p += __shfl_xor(p, 4, 16);
                    p += __shfl_xor(p, 8, 16);
                    if ((lane & 15) == 0) spw[(base + j) * NH + hh] = p;
                    float mn = fmaxf(m, p);
                    float sc = EXP2(m - mn);
                    float w  = EXP2(p - mn);
                    lsum = lsum * sc + w;
                    acc0 = acc0 * sc + w * evx;
                    acc1 = acc1 * sc + w * evy;
                    m = mn;
                }
            }
            si = si_nxt;
        }
    } else if (deg > DEGCAP) {
        // fallback pass 1: online softmax only (no score stash)
        ushort2 u = {0,0};
        { int s_ = epair[lo].y; u = *(const ushort2*)(el_bf + (size_t)s_ * HD + l2); }
        for (int i = lo; i < hi; ++i) {
            float evx = bf2f(u.x), evy = bf2f(u.y);
            if (i + 1 < hi) { int s_ = epair[i + 1].y;
                u = *(const ushort2*)(el_bf + (size_t)s_ * HD + l2); }
            float x0 = evx + rv.x; x0 = fmaxf(x0, NEG * x0);
            float x1 = evy + rv.y; x1 = fmaxf(x1, NEG * x1);
            float p = x0 * a0 + x1 * a1;
            p += __shfl_xor(p, 1, 16);
            p += __shfl_xor(p, 2, 16);
            p += __shfl_xor(p, 4, 16);
            p += __shfl_xor(p, 8, 16);
            float mn = fmaxf(m, p);
            float sc = EXP2(m - mn);
            float w  = EXP2(p - mn);
            lsum = lsum * sc + w;
            acc0 = acc0 * sc + w * evx;
            acc1 = acc1 * sc + w * evy;
            m = mn;
        }
    }

    // write aggregated features
    float2 o;
    if (deg == 0) { o.x = 0.0f; o.y = 0.0f; }
    else { float inv = 1.0f / lsum; o.x = acc0 * inv; o.y = acc1 * inv; }
    *(float2*)(out_feat + (size_t)n * HD + l2) = o;

    if (deg == 0) return;

    // normalize + write attention weights
    float inv = 1.0f / lsum;
    if (deg <= DEGCAP) {
        // broadcast (m, inv) of head (lane&3) from its group (values uniform in group)
        float mh   = __shfl(m,   (lane & 3) << 4, 64);
        float invh = __shfl(inv, (lane & 3) << 4, 64);
        for (int q = (lane >> 2); q < deg; q += 16) {
            int e = epair[lo + q].x;
            float p = spw[q * NH + (lane & 3)];
            out_a[(size_t)e * NH + (lane & 3)] = EXP2(p - mh) * invh;
        }
    } else {
        // fallback pass 2: recompute scores and write a
        for (int i = lo; i < hi; ++i) {
            int s_ = epair[i].y;
            ushort2 u = *(const ushort2*)(el_bf + (size_t)s_ * HD + l2);
            float evx = bf2f(u.x), evy = bf2f(u.y);
            float x0 = evx + rv.x; x0 = fmaxf(x0, NEG * x0);
            float x1 = evy + rv.y; x1 = fmaxf(x1, NEG * x1);
            float p = x0 * a0 + x1 * a1;
            p += __shfl_xor(p, 1, 16);
            p += __shfl_xor(p, 2, 16);
            p += __shfl_xor(p, 4, 16);
            p += __shfl_xor(p, 8, 16);
            if ((lane & 15) == 0) {
                int e = epair[i].x;
                out_a[(size_t)e * NH + hh] = EXP2(p - m) * inv;
            }
        }
    }
}

extern "C" void kernel_launch(void* const* d_in, const int* in_sizes, int n_in,
                              void* d_out, int out_size, void* d_ws, size_t ws_size,
                              hipStream_t stream) {
    const float* h    = (const float*)d_in[0];
    const int*   src  = (const int*)d_in[1];
    const int*   dst  = (const int*)d_in[2];
    const float* Wsrc = (const float*)d_in[3];
    const float* bsrc = (const float*)d_in[4];
    const float* Wdst = (const float*)d_in[5];
    const float* bdst = (const float*)d_in[6];
    const float* attn = (const float*)d_in[7];

    float* out_feat = (float*)d_out;                       // N*128
    float* out_a    = out_feat + (size_t)NNODES * HD;      // E*4

    // workspace layout (16B-aligned chunks), ~45 MB total
    float*  er       = (float*)d_ws;                         // N*128 f32 (25.6 MB)
    ushort* Wt       = (ushort*)(er + (size_t)NNODES * HD);  // 256*256 bf16
    ushort* el_bf    = Wt + 2 * HD * INDIM;                  // N*128 bf16 (12.8 MB)
    int*    cnt_work = (int*)(el_bf + (size_t)NNODES * HD);  // N
    int2*   epair    = (int2*)(cnt_work + NNODES);           // E {eidx, esrc} (6.4 MB)
    int*    rowptr   = (int*)(epair + NEDGES);               // N+1
    int*    partials = rowptr + NNODES + 1;                  // SCAN_B

    // 1) fusedPre: clear cnt | W convert+transpose
    fusedPre_kernel<<<CLR_BLKS + CONVW_BLKS, 256, 0, stream>>>(
        cnt_work, Wsrc, Wdst, Wt);

    // 2) fusedG: MFMA GEMM 128x256 (el, er) | hist (independent -> overlapped)
    fusedG_kernel<<<GEMM_BLKS + HIST_BLKS, 256, 0, stream>>>(
        h, Wt, bsrc, bdst, el_bf, er, dst, cnt_work);

    // 3-4) 2-kernel scan chain -> rowptr + scatter cursors
    scan_partial_kernel<<<SCAN_B, 256, 0, stream>>>(cnt_work, partials);
    scan_final_kernel<<<SCAN_B, 256, 0, stream>>>(cnt_work, partials, rowptr);

    // 5) scatter: standalone, full occupancy
    scatter_kernel<<<SCAT_BLKS, 256, 0, stream>>>(src, dst, cnt_work, epair);

    // 6) node_fused
    node_fused_kernel<<<(NNODES + 3) / 4, 256, 0, stream>>>(
        el_bf, er, rowptr, epair, attn, out_feat, out_a);
}

// Round 15
// 267.112 us; speedup vs baseline: 1.0026x; 1.0026x over previous
//
#include <hip/hip_runtime.h>
#include <cstdint>
#include <cstddef>

#define NNODES 50000
#define NEDGES 800000
#define INDIM  256
#define HD     128   // H*D
#define NH     4
#define NEG    0.2f
#define LOG2E  1.44269504088896340736f

#define PAD    16    // ints per counter slot: one 64B line per node (anti-serialization)

#define SCAN_B ((NNODES + 255) / 256)   // 196 blocks

// fusedPre partition (clear cnt_pad | conv_w)
#define CLR_BLKS   ((NNODES * PAD / 4 + 255) / 256)  // 782
#define CONVW_BLKS 64
// fusedG block partition (gemm 128x256 | hist 8 edges/thread)
#define GEMM_BLKS  ((NNODES + 127) / 128)           // 391
#define HIST_BLKS  ((NEDGES + 2047) / 2048)         // 391
// scatter standalone
#define SCAT_BLKS  ((NEDGES + 2047) / 2048)         // 391

typedef __attribute__((ext_vector_type(8))) short   short8;   // 8 bf16 (4 VGPRs)
typedef __attribute__((ext_vector_type(8))) ushort  ushort8;
typedef __attribute__((ext_vector_type(4))) float   floatx4;

// fast hardware exp2: single v_exp_f32 (exp2f() is the libm-accurate path and
// cost +8 VGPR / +18% VALU cycles in r12 -- do not use it here)
#define EXP2(x) __builtin_amdgcn_exp2f(x)

// f32 -> bf16 (round-to-nearest-even), raw bits
__device__ __forceinline__ ushort f2bf(float f) {
    unsigned u = __float_as_uint(f);
    unsigned r = u + 0x7fffu + ((u >> 16) & 1u);
    return (ushort)(r >> 16);
}
__device__ __forceinline__ float bf2f(ushort u) {
    return __uint_as_float(((unsigned)u) << 16);
}

// LDS chunk swizzle: conflict-free staging writes + fragment reads
__device__ __forceinline__ int swz(int c) { return c ^ ((c >> 4) & 7); }

// ================= fusedPre: clear cnt_pad | W convert+transpose =================
__global__ __launch_bounds__(256) void fusedPre_kernel(
        int* __restrict__ cnt_work,
        const float* __restrict__ Wsrc, const float* __restrict__ Wdst,
        ushort* __restrict__ Wt) {
    __shared__ float t[32][33];
    const int bid = blockIdx.x;
    const int tid = threadIdx.x;

    if (bid < CLR_BLKS) {
        int i = bid * 256 + tid;
        if (i < NNODES * PAD / 4)
            ((int4*)cnt_work)[i] = make_int4(0, 0, 0, 0);
        return;
    }
    // ---- W convert+transpose (LDS-tiled): Wt[n][k] bf16 ----
    int wb = bid - CLR_BLKS;                      // 0..63
    int kb = (wb & 7) * 32, nb = (wb >> 3) * 32;
    int tx = tid & 31, ty = tid >> 5;
    for (int i = ty; i < 32; i += 8) {
        int k = kb + i, n = nb + tx;
        float v = (n < HD) ? Wsrc[(size_t)k * HD + n] : Wdst[(size_t)k * HD + (n - HD)];
        t[i][tx] = v;
    }
    __syncthreads();
    for (int i = ty; i < 32; i += 8) {
        int n = nb + i, k = kb + tx;
        Wt[(size_t)n * INDIM + k] = f2bf(t[tx][i]);
    }
}

// ================= fusedG: MFMA GEMM (128x256, f32 A direct) | hist (padded) ========
// GEMM needs only convw+h; hist needs only cleared cnt_pad -> overlapped.
// hist atomics target cnt_pad[dst*PAD]: ONE 64B line per node (was 16 nodes/line ->
// ~256 same-line atomics serializing at the coherence point; r14's occupancy
// experiment proved the wall is NOT wave count).
__global__ __launch_bounds__(256, 2) void fusedG_kernel(
        const float* __restrict__ h, const ushort* __restrict__ Wt,
        const float* __restrict__ bsrc, const float* __restrict__ bdst,
        ushort* __restrict__ el_bf, float* __restrict__ er,
        const int* __restrict__ dst, int* __restrict__ cnt_work) {
    __shared__ ushort As[512 * 8];    // 128 rows x 32 k bf16 (8 KB)
    __shared__ ushort Bs[1024 * 8];   // 256 cols x 32 k bf16 (16 KB)

    const int bid = blockIdx.x;
    const int tid = threadIdx.x;

    if (bid >= GEMM_BLKS) {
        // ---- hist: 8 edges/thread (stride-256, coalesced), non-returning atomics ----
        int base = (bid - GEMM_BLKS) * 2048 + tid;
        int dd[8];
#pragma unroll
        for (int k = 0; k < 8; ++k) {
            int e = base + k * 256;
            dd[k] = (e < NEDGES) ? dst[e] : -1;
        }
#pragma unroll
        for (int k = 0; k < 8; ++k) {
            if (dd[k] >= 0) atomicAdd(cnt_work + (size_t)dd[k] * PAD, 1);
        }
        return;
    }

    const int wave = tid >> 6, lane = tid & 63;
    const int row0 = bid * 128;
    const int l15  = lane & 15, quad = lane >> 4;

    floatx4 acc[2][16];
#pragma unroll
    for (int i = 0; i < 2; ++i)
#pragma unroll
        for (int j = 0; j < 16; ++j) acc[i][j] = (floatx4){0.f, 0.f, 0.f, 0.f};

    for (int kk = 0; kk < INDIM; kk += 32) {
        // ---- A staging: 512 chunks of 8, f32 source + convert ----
#pragma unroll
        for (int it = 0; it < 2; ++it) {
            int idx = tid + it * 256;    // 0..511
            int r = idx >> 2;            // 0..127 (row)
            int kq = idx & 3;            // k-quad (8 elems)
            int c = (r >> 4) * 64 + kq * 16 + (r & 15);
            int grow = row0 + r;
            ushort8 aw = (ushort8){0,0,0,0,0,0,0,0};
            if (grow < NNODES) {
                const float* p = h + (size_t)grow * INDIM + kk + kq * 8;
                float4 v0 = *(const float4*)p;
                float4 v1 = *(const float4*)(p + 4);
                aw[0] = f2bf(v0.x); aw[1] = f2bf(v0.y); aw[2] = f2bf(v0.z); aw[3] = f2bf(v0.w);
                aw[4] = f2bf(v1.x); aw[5] = f2bf(v1.y); aw[6] = f2bf(v1.z); aw[7] = f2bf(v1.w);
            }
            *(ushort8*)(As + swz(c) * 8) = aw;
        }
        // ---- B staging: 1024 chunks of 8 (256 cols) ----
#pragma unroll
        for (int it = 0; it < 4; ++it) {
            int idx = tid + it * 256;    // 0..1023
            int r = idx >> 2;            // 0..255 (col)
            int kq = idx & 3;
            int c = (r >> 4) * 64 + kq * 16 + (r & 15);   // 0..1023
            ushort8 bw = *(const ushort8*)(Wt + (size_t)r * INDIM + kk + kq * 8);
            *(ushort8*)(Bs + swz(c) * 8) = bw;
        }
        __syncthreads();

        short8 af[2];
#pragma unroll
        for (int tm = 0; tm < 2; ++tm) {
            int c = (wave * 2 + tm) * 64 + quad * 16 + l15;
            af[tm] = *(const short8*)(As + swz(c) * 8);
        }
#pragma unroll
        for (int tn = 0; tn < 16; ++tn) {
            int c = tn * 64 + quad * 16 + l15;
            short8 bfr = *(const short8*)(Bs + swz(c) * 8);
            acc[0][tn] = __builtin_amdgcn_mfma_f32_16x16x32_bf16(af[0], bfr, acc[0][tn], 0, 0, 0);
            acc[1][tn] = __builtin_amdgcn_mfma_f32_16x16x32_bf16(af[1], bfr, acc[1][tn], 0, 0, 0);
        }
        __syncthreads();
    }

    // epilogue: C/D layout col=lane&15, row=quad*4+reg
#pragma unroll
    for (int tn = 0; tn < 8; ++tn) {
        int col = tn * 16 + l15;              // 0..127 -> el
        float bias = bsrc[col];
#pragma unroll
        for (int tm = 0; tm < 2; ++tm)
#pragma unroll
            for (int reg = 0; reg < 4; ++reg) {
                int row = row0 + wave * 32 + tm * 16 + quad * 4 + reg;
                if (row < NNODES)
                    el_bf[(size_t)row * HD + col] = f2bf(acc[tm][tn][reg] + bias);
            }
    }
#pragma unroll
    for (int tn = 8; tn < 16; ++tn) {
        int col = tn * 16 + l15 - HD;         // 0..127 -> er
        float bias = bdst[col];
#pragma unroll
        for (int tm = 0; tm < 2; ++tm)
#pragma unroll
            for (int reg = 0; reg < 4; ++reg) {
                int row = row0 + wave * 32 + tm * 16 + quad * 4 + reg;
                if (row < NNODES)
                    er[(size_t)row * HD + col] = acc[tm][tn][reg] + bias;
            }
    }
}

// ================= CSR scan: 2-kernel chain (padded counter reads) =================
__global__ __launch_bounds__(256) void scan_partial_kernel(
        const int* __restrict__ cnt, int* __restrict__ partials) {
    __shared__ int lds[256];
    int i = blockIdx.x * 256 + threadIdx.x;
    lds[threadIdx.x] = (i < NNODES) ? cnt[(size_t)i * PAD] : 0;
    __syncthreads();
    for (int off = 128; off > 0; off >>= 1) {
        if (threadIdx.x < off) lds[threadIdx.x] += lds[threadIdx.x + off];
        __syncthreads();
    }
    if (threadIdx.x == 0) partials[blockIdx.x] = lds[0];
}

__global__ __launch_bounds__(256) void scan_final_kernel(
        int* __restrict__ cnt_work, const int* __restrict__ partials,
        int* __restrict__ rowptr) {
    __shared__ int lds[256];
    __shared__ int sh_prefix;
    const int t = threadIdx.x;
    const int bid = blockIdx.x;

    // prefix = sum of partials[0..bid-1]  (bid <= 195 < 256)
    int pv = (t < bid) ? partials[t] : 0;
    lds[t] = pv;
    __syncthreads();
    for (int off = 128; off > 0; off >>= 1) {
        if (t < off) lds[t] += lds[t + off];
        __syncthreads();
    }
    if (t == 0) sh_prefix = lds[0];
    __syncthreads();
    const int prefix = sh_prefix;
    __syncthreads();                       // lds reuse barrier

    const int i = bid * 256 + t;
    int v = (i < NNODES) ? cnt_work[(size_t)i * PAD] : 0;
    lds[t] = v;
    __syncthreads();
    for (int off = 1; off < 256; off <<= 1) {
        int u = (t >= off) ? lds[t - off] : 0;
        __syncthreads();
        lds[t] += u;
        __syncthreads();
    }
    if (i < NNODES) {
        int start = prefix + lds[t] - v;   // exclusive + global prefix
        rowptr[i] = start;
        cnt_work[(size_t)i * PAD] = start; // scatter cursor (padded slot)
    }
    if (bid == SCAN_B - 1 && t == 255) rowptr[NNODES] = prefix + lds[255];
}

// ================= scatter: standalone, padded cursors =================
__global__ __launch_bounds__(256) void scatter_kernel(
        const int* __restrict__ src, const int* __restrict__ dst,
        int* __restrict__ cnt_work, int2* __restrict__ epair) {
    int base = blockIdx.x * 2048 + threadIdx.x;
    int ss[8], dd[8], pos[8];
#pragma unroll
    for (int k = 0; k < 8; ++k) {
        int e = base + k * 256;
        if (e < NEDGES) { ss[k] = src[e]; dd[k] = dst[e]; } else dd[k] = -1;
    }
#pragma unroll
    for (int k = 0; k < 8; ++k) {
        if (dd[k] >= 0) pos[k] = atomicAdd(cnt_work + (size_t)dd[k] * PAD, 1);
    }
#pragma unroll
    for (int k = 0; k < 8; ++k) {
        int e = base + k * 256;
        if (dd[k] >= 0) epair[pos[k]] = make_int2(e, ss[k]);
    }
}

// ================= node_fused: proven branchless body, er aliased into out_feat ====
// one wave per node; lane l owns dims 2l,2l+1; head hh = l>>4. CSR int2 epair.
// erout = out_feat region: er[n] is read by node n's own wave BEFORE it overwrites
// the same bytes (identical layout; proven safe r7-r9). EXP2 = raw v_exp_f32.
// Body shape is the proven form -- do NOT restructure.
#define DEGCAP 128

__global__ __launch_bounds__(256) void node_fused_kernel(
        const ushort* __restrict__ el_bf, float* __restrict__ erout,
        const int* __restrict__ rowptr, const int2* __restrict__ epair,
        const float* __restrict__ attn, float* __restrict__ out_a) {
    __shared__ float sp[4][DEGCAP * NH];   // 2 KB per wave

    const int wv = threadIdx.x >> 6;
    const int n = blockIdx.x * 4 + wv;
    if (n >= NNODES) return;
    const int lane = threadIdx.x & 63;
    const int hh = lane >> 4;
    const int lo = rowptr[n], hi = rowptr[n + 1];
    const int deg = hi - lo;
    float* spw = sp[wv];
    const int l2 = lane * 2;

    const float2 rv = *(const float2*)(erout + (size_t)n * HD + l2);
    const float a0 = attn[l2] * LOG2E, a1 = attn[l2 + 1] * LOG2E;

    float m = -3.4e38f, lsum = 0.0f, acc0 = 0.0f, acc1 = 0.0f;

    if (deg > 0 && deg <= DEGCAP) {
        // preload first chunk of up to 16 edge-source indices (coalesced, clamped)
        int jj0 = (lane & 15);
        if (jj0 >= deg) jj0 = deg - 1;
        int si = epair[lo + jj0].y;

        for (int base = 0; base < deg; base += 16) {
            // issue all gathers of this chunk (wave-uniform scalar base per edge)
            ushort2 u[16];
#pragma unroll
            for (int j = 0; j < 16; ++j) {
                if (base + j < deg) {
                    int s = __builtin_amdgcn_readlane(si, j);
                    u[j] = *(const ushort2*)(el_bf + (size_t)s * HD + l2);
                }
            }
            // prefetch next chunk's indices (hides index-load latency under compute)
            int si_nxt = si;
            if (base + 16 < deg) {
                int jj = base + 16 + (lane & 15);
                if (jj >= deg) jj = deg - 1;
                si_nxt = epair[lo + jj].y;
            }
            // process chunk: per-edge, branchless online softmax (proven shape)
#pragma unroll
            for (int j = 0; j < 16; ++j) {
                if (base + j < deg) {
                    float evx = bf2f(u[j].x), evy = bf2f(u[j].y);
                    float x0 = evx + rv.x; x0 = fmaxf(x0, NEG * x0);
                    float x1 = evy + rv.y; x1 = fmaxf(x1, NEG * x1);
                    float p = x0 * a0 + x1 * a1;        // log2-domain score
                    p += __shfl_xor(p, 1, 16);
                    p += __shfl_xor(p, 2, 16);
                    p += __shfl_xor(p, 4, 16);
                    p += __shfl_xor(p, 8, 16);
                    if ((lane & 15) == 0) spw[(base + j) * NH + hh] = p;
                    float mn = fmaxf(m, p);
                    float sc = EXP2(m - mn);
                    float w  = EXP2(p - mn);
                    lsum = lsum * sc + w;
                    acc0 = acc0 * sc + w * evx;
                    acc1 = acc1 * sc + w * evy;
                    m = mn;
                }
            }
            si = si_nxt;
        }
    } else if (deg > DEGCAP) {
        // fallback pass 1: online softmax only (no score stash)
        ushort2 u = {0,0};
        { int s_ = epair[lo].y; u = *(const ushort2*)(el_bf + (size_t)s_ * HD + l2); }
        for (int i = lo; i < hi; ++i) {
            float evx = bf2f(u.x), evy = bf2f(u.y);
            if (i + 1 < hi) { int s_ = epair[i + 1].y;
                u = *(const ushort2*)(el_bf + (size_t)s_ * HD + l2); }
            float x0 = evx + rv.x; x0 = fmaxf(x0, NEG * x0);
            float x1 = evy + rv.y; x1 = fmaxf(x1, NEG * x1);
            float p = x0 * a0 + x1 * a1;
            p += __shfl_xor(p, 1, 16);
            p += __shfl_xor(p, 2, 16);
            p += __shfl_xor(p, 4, 16);
            p += __shfl_xor(p, 8, 16);
            float mn = fmaxf(m, p);
            float sc = EXP2(m - mn);
            float w  = EXP2(p - mn);
            lsum = lsum * sc + w;
            acc0 = acc0 * sc + w * evx;
            acc1 = acc1 * sc + w * evy;
            m = mn;
        }
    }

    // write aggregated features (overwrites er[n] -- same bytes, own wave)
    float2 o;
    if (deg == 0) { o.x = 0.0f; o.y = 0.0f; }
    else { float inv = 1.0f / lsum; o.x = acc0 * inv; o.y = acc1 * inv; }
    *(float2*)(erout + (size_t)n * HD + l2) = o;

    if (deg == 0) return;

    // normalize + write attention weights
    float inv = 1.0f / lsum;
    if (deg <= DEGCAP) {
        // broadcast (m, inv) of head (lane&3) from its group (values uniform in group)
        float mh   = __shfl(m,   (lane & 3) << 4, 64);
        float invh = __shfl(inv, (lane & 3) << 4, 64);
        for (int q = (lane >> 2); q < deg; q += 16) {
            int e = epair[lo + q].x;
            float p = spw[q * NH + (lane & 3)];
            out_a[(size_t)e * NH + (lane & 3)] = EXP2(p - mh) * invh;
        }
    } else {
        // fallback pass 2: recompute scores and write a
        for (int i = lo; i < hi; ++i) {
            int s_ = epair[i].y;
            ushort2 u = *(const ushort2*)(el_bf + (size_t)s_ * HD + l2);
            float evx = bf2f(u.x), evy = bf2f(u.y);
            float x0 = evx + rv.x; x0 = fmaxf(x0, NEG * x0);
            float x1 = evy + rv.y; x1 = fmaxf(x1, NEG * x1);
            float p = x0 * a0 + x1 * a1;
            p += __shfl_xor(p, 1, 16);
            p += __shfl_xor(p, 2, 16);
            p += __shfl_xor(p, 4, 16);
            p += __shfl_xor(p, 8, 16);
            if ((lane & 15) == 0) {
                int e = epair[i].x;
                out_a[(size_t)e * NH + hh] = EXP2(p - m) * inv;
            }
        }
    }
}

extern "C" void kernel_launch(void* const* d_in, const int* in_sizes, int n_in,
                              void* d_out, int out_size, void* d_ws, size_t ws_size,
                              hipStream_t stream) {
    const float* h    = (const float*)d_in[0];
    const int*   src  = (const int*)d_in[1];
    const int*   dst  = (const int*)d_in[2];
    const float* Wsrc = (const float*)d_in[3];
    const float* bsrc = (const float*)d_in[4];
    const float* Wdst = (const float*)d_in[5];
    const float* bdst = (const float*)d_in[6];
    const float* attn = (const float*)d_in[7];

    float* out_feat = (float*)d_out;                       // N*128 (er aliased here)
    float* out_a    = out_feat + (size_t)NNODES * HD;      // E*4

    // workspace layout (16B-aligned chunks), ~22.8 MB total
    ushort* Wt       = (ushort*)d_ws;                        // 256*256 bf16 (128 KB)
    ushort* el_bf    = Wt + 2 * HD * INDIM;                  // N*128 bf16 (12.8 MB)
    int*    cnt_work = (int*)(el_bf + (size_t)NNODES * HD);  // N*PAD ints (3.2 MB)
    int2*   epair    = (int2*)(cnt_work + (size_t)NNODES * PAD); // E {eidx,esrc} (6.4 MB)
    int*    rowptr   = (int*)(epair + NEDGES);               // N+1
    int*    partials = rowptr + NNODES + 1;                  // SCAN_B

    // 1) fusedPre: clear cnt_pad | W convert+transpose
    fusedPre_kernel<<<CLR_BLKS + CONVW_BLKS, 256, 0, stream>>>(
        cnt_work, Wsrc, Wdst, Wt);

    // 2) fusedG: MFMA GEMM 128x256 (el -> ws, er -> d_out) | hist (padded counters)
    fusedG_kernel<<<GEMM_BLKS + HIST_BLKS, 256, 0, stream>>>(
        h, Wt, bsrc, bdst, el_bf, out_feat, dst, cnt_work);

    // 3-4) 2-kernel scan chain -> rowptr + padded scatter cursors
    scan_partial_kernel<<<SCAN_B, 256, 0, stream>>>(cnt_work, partials);
    scan_final_kernel<<<SCAN_B, 256, 0, stream>>>(cnt_work, partials, rowptr);

    // 5) scatter: standalone, padded cursors
    scatter_kernel<<<SCAT_BLKS, 256, 0, stream>>>(src, dst, cnt_work, epair);

    // 6) node_fused (erout = out_feat)
    node_fused_kernel<<<(NNODES + 3) / 4, 256, 0, stream>>>(
        el_bf, out_feat, rowptr, epair, attn, out_a);
}

// Round 16
// 237.028 us; speedup vs baseline: 1.1299x; 1.1269x over previous
//
#include <hip/hip_runtime.h>
#include <cstdint>
#include <cstddef>

#define NNODES 50000
#define NEDGES 800000
#define INDIM  256
#define HD     128   // H*D
#define NH     4
#define NEG    0.2f
#define LOG2E  1.44269504088896340736f

#define SCAN_B ((NNODES + 255) / 256)   // 196 blocks

// fusedPre partition (clear cnt | conv_w)
#define CLR_BLKS   49                               // 12544 int4 slots >= 12500
#define CONVW_BLKS 64
// fusedG block partition (gemm 128x256 | rank-pass 8 edges/thread)
#define GEMM_BLKS  ((NNODES + 127) / 128)           // 391
#define RANK_BLKS  ((NEDGES + 2047) / 2048)         // 391
// scatter (no atomics) standalone
#define SCAT_BLKS  ((NEDGES + 2047) / 2048)         // 391

typedef __attribute__((ext_vector_type(8))) short   short8;   // 8 bf16 (4 VGPRs)
typedef __attribute__((ext_vector_type(8))) ushort  ushort8;
typedef __attribute__((ext_vector_type(4))) float   floatx4;

// fast hardware exp2: single v_exp_f32 (exp2f() is the libm-accurate path and
// cost +8 VGPR / +18% VALU cycles in r12 -- do not use it here)
#define EXP2(x) __builtin_amdgcn_exp2f(x)

// f32 -> bf16 (round-to-nearest-even), raw bits
__device__ __forceinline__ ushort f2bf(float f) {
    unsigned u = __float_as_uint(f);
    unsigned r = u + 0x7fffu + ((u >> 16) & 1u);
    return (ushort)(r >> 16);
}
__device__ __forceinline__ float bf2f(ushort u) {
    return __uint_as_float(((unsigned)u) << 16);
}

// LDS chunk swizzle: conflict-free staging writes + fragment reads
__device__ __forceinline__ int swz(int c) { return c ^ ((c >> 4) & 7); }

// ================= fusedPre: clear cnt | W convert+transpose =================
__global__ __launch_bounds__(256) void fusedPre_kernel(
        int* __restrict__ cnt_work,
        const float* __restrict__ Wsrc, const float* __restrict__ Wdst,
        ushort* __restrict__ Wt) {
    __shared__ float t[32][33];
    const int bid = blockIdx.x;
    const int tid = threadIdx.x;

    if (bid < CLR_BLKS) {
        int i = bid * 256 + tid;
        if (i < (NNODES + 3) / 4)
            ((int4*)cnt_work)[i] = make_int4(0, 0, 0, 0);
        return;
    }
    // ---- W convert+transpose (LDS-tiled): Wt[n][k] bf16 ----
    int wb = bid - CLR_BLKS;                      // 0..63
    int kb = (wb & 7) * 32, nb = (wb >> 3) * 32;
    int tx = tid & 31, ty = tid >> 5;
    for (int i = ty; i < 32; i += 8) {
        int k = kb + i, n = nb + tx;
        float v = (n < HD) ? Wsrc[(size_t)k * HD + n] : Wdst[(size_t)k * HD + (n - HD)];
        t[i][tx] = v;
    }
    __syncthreads();
    for (int i = ty; i < 32; i += 8) {
        int n = nb + i, k = kb + tx;
        Wt[(size_t)n * INDIM + k] = f2bf(t[tx][i]);
    }
}

// ================= fusedG: MFMA GEMM (128x256, f32 A direct) | rank-pass ===========
// THE structural change (r15 post-mortem): the pipeline paid the ~12 G atomics/s
// device-scope fabric wall TWICE (non-returning hist + returning scatter, ~65us
// each; ILP/occupancy/line-padding all measured null). The rank-pass makes the
// ONE atomic pass returning -- rank[e] = old count -- so the scatter needs NO
// atomics at all (pos = rowptr[dst] + rank). Upper bound: r13's measured
// GEMM||returning-scatter = 74.5us, and this writes coalesced 4B instead of
// scattered 8B.
__global__ __launch_bounds__(256, 2) void fusedG_kernel(
        const float* __restrict__ h, const ushort* __restrict__ Wt,
        const float* __restrict__ bsrc, const float* __restrict__ bdst,
        ushort* __restrict__ el_bf, float* __restrict__ er,
        const int* __restrict__ dst, int* __restrict__ cnt_work,
        int* __restrict__ rank) {
    __shared__ ushort As[512 * 8];    // 128 rows x 32 k bf16 (8 KB)
    __shared__ ushort Bs[1024 * 8];   // 256 cols x 32 k bf16 (16 KB)

    const int bid = blockIdx.x;
    const int tid = threadIdx.x;

    if (bid >= GEMM_BLKS) {
        // ---- rank-pass: 8 edges/thread (stride-256, coalesced), returning atomics ----
        int base = (bid - GEMM_BLKS) * 2048 + tid;
        int dd[8], pos[8];
#pragma unroll
        for (int k = 0; k < 8; ++k) {
            int e = base + k * 256;
            dd[k] = (e < NEDGES) ? dst[e] : -1;
        }
#pragma unroll
        for (int k = 0; k < 8; ++k) {
            if (dd[k] >= 0) pos[k] = atomicAdd(cnt_work + dd[k], 1);
        }
#pragma unroll
        for (int k = 0; k < 8; ++k) {
            int e = base + k * 256;
            if (dd[k] >= 0) rank[e] = pos[k];     // coalesced 4B store
        }
        return;
    }

    const int wave = tid >> 6, lane = tid & 63;
    const int row0 = bid * 128;
    const int l15  = lane & 15, quad = lane >> 4;

    floatx4 acc[2][16];
#pragma unroll
    for (int i = 0; i < 2; ++i)
#pragma unroll
        for (int j = 0; j < 16; ++j) acc[i][j] = (floatx4){0.f, 0.f, 0.f, 0.f};

    for (int kk = 0; kk < INDIM; kk += 32) {
        // ---- A staging: 512 chunks of 8, f32 source + convert ----
#pragma unroll
        for (int it = 0; it < 2; ++it) {
            int idx = tid + it * 256;    // 0..511
            int r = idx >> 2;            // 0..127 (row)
            int kq = idx & 3;            // k-quad (8 elems)
            int c = (r >> 4) * 64 + kq * 16 + (r & 15);
            int grow = row0 + r;
            ushort8 aw = (ushort8){0,0,0,0,0,0,0,0};
            if (grow < NNODES) {
                const float* p = h + (size_t)grow * INDIM + kk + kq * 8;
                float4 v0 = *(const float4*)p;
                float4 v1 = *(const float4*)(p + 4);
                aw[0] = f2bf(v0.x); aw[1] = f2bf(v0.y); aw[2] = f2bf(v0.z); aw[3] = f2bf(v0.w);
                aw[4] = f2bf(v1.x); aw[5] = f2bf(v1.y); aw[6] = f2bf(v1.z); aw[7] = f2bf(v1.w);
            }
            *(ushort8*)(As + swz(c) * 8) = aw;
        }
        // ---- B staging: 1024 chunks of 8 (256 cols) ----
#pragma unroll
        for (int it = 0; it < 4; ++it) {
            int idx = tid + it * 256;    // 0..1023
            int r = idx >> 2;            // 0..255 (col)
            int kq = idx & 3;
            int c = (r >> 4) * 64 + kq * 16 + (r & 15);   // 0..1023
            ushort8 bw = *(const ushort8*)(Wt + (size_t)r * INDIM + kk + kq * 8);
            *(ushort8*)(Bs + swz(c) * 8) = bw;
        }
        __syncthreads();

        short8 af[2];
#pragma unroll
        for (int tm = 0; tm < 2; ++tm) {
            int c = (wave * 2 + tm) * 64 + quad * 16 + l15;
            af[tm] = *(const short8*)(As + swz(c) * 8);
        }
#pragma unroll
        for (int tn = 0; tn < 16; ++tn) {
            int c = tn * 64 + quad * 16 + l15;
            short8 bfr = *(const short8*)(Bs + swz(c) * 8);
            acc[0][tn] = __builtin_amdgcn_mfma_f32_16x16x32_bf16(af[0], bfr, acc[0][tn], 0, 0, 0);
            acc[1][tn] = __builtin_amdgcn_mfma_f32_16x16x32_bf16(af[1], bfr, acc[1][tn], 0, 0, 0);
        }
        __syncthreads();
    }

    // epilogue: C/D layout col=lane&15, row=quad*4+reg
#pragma unroll
    for (int tn = 0; tn < 8; ++tn) {
        int col = tn * 16 + l15;              // 0..127 -> el
        float bias = bsrc[col];
#pragma unroll
        for (int tm = 0; tm < 2; ++tm)
#pragma unroll
            for (int reg = 0; reg < 4; ++reg) {
                int row = row0 + wave * 32 + tm * 16 + quad * 4 + reg;
                if (row < NNODES)
                    el_bf[(size_t)row * HD + col] = f2bf(acc[tm][tn][reg] + bias);
            }
    }
#pragma unroll
    for (int tn = 8; tn < 16; ++tn) {
        int col = tn * 16 + l15 - HD;         // 0..127 -> er
        float bias = bdst[col];
#pragma unroll
        for (int tm = 0; tm < 2; ++tm)
#pragma unroll
            for (int reg = 0; reg < 4; ++reg) {
                int row = row0 + wave * 32 + tm * 16 + quad * 4 + reg;
                if (row < NNODES)
                    er[(size_t)row * HD + col] = acc[tm][tn][reg] + bias;
            }
    }
}

// ================= CSR scan: 2-kernel chain (dense counters) =================
__global__ __launch_bounds__(256) void scan_partial_kernel(
        const int* __restrict__ cnt, int* __restrict__ partials) {
    __shared__ int lds[256];
    int i = blockIdx.x * 256 + threadIdx.x;
    lds[threadIdx.x] = (i < NNODES) ? cnt[i] : 0;
    __syncthreads();
    for (int off = 128; off > 0; off >>= 1) {
        if (threadIdx.x < off) lds[threadIdx.x] += lds[threadIdx.x + off];
        __syncthreads();
    }
    if (threadIdx.x == 0) partials[blockIdx.x] = lds[0];
}

__global__ __launch_bounds__(256) void scan_final_kernel(
        const int* __restrict__ cnt_work, const int* __restrict__ partials,
        int* __restrict__ rowptr) {
    __shared__ int lds[256];
    __shared__ int sh_prefix;
    const int t = threadIdx.x;
    const int bid = blockIdx.x;

    // prefix = sum of partials[0..bid-1]  (bid <= 195 < 256)
    int pv = (t < bid) ? partials[t] : 0;
    lds[t] = pv;
    __syncthreads();
    for (int off = 128; off > 0; off >>= 1) {
        if (t < off) lds[t] += lds[t + off];
        __syncthreads();
    }
    if (t == 0) sh_prefix = lds[0];
    __syncthreads();
    const int prefix = sh_prefix;
    __syncthreads();                       // lds reuse barrier

    const int i = bid * 256 + t;
    int v = (i < NNODES) ? cnt_work[i] : 0;
    lds[t] = v;
    __syncthreads();
    for (int off = 1; off < 256; off <<= 1) {
        int u = (t >= off) ? lds[t - off] : 0;
        __syncthreads();
        lds[t] += u;
        __syncthreads();
    }
    if (i < NNODES)
        rowptr[i] = prefix + lds[t] - v;   // exclusive + global prefix
    if (bid == SCAN_B - 1 && t == 255) rowptr[NNODES] = prefix + lds[255];
}

// ================= scatter: NO atomics (pos = rowptr[dst] + rank) =================
// Pure gather (rowptr = 200KB, L2-resident) + scattered 8B store. The returning
// atomic that used to compute pos was absorbed into the rank-pass.
__global__ __launch_bounds__(256) void scatter_kernel(
        const int* __restrict__ src, const int* __restrict__ dst,
        const int* __restrict__ rank, const int* __restrict__ rowptr,
        int2* __restrict__ epair) {
    int base = blockIdx.x * 2048 + threadIdx.x;
    int ss[8], dd[8], rk[8];
#pragma unroll
    for (int k = 0; k < 8; ++k) {
        int e = base + k * 256;
        if (e < NEDGES) { ss[k] = src[e]; dd[k] = dst[e]; rk[k] = rank[e]; }
        else dd[k] = -1;
    }
    int pos[8];
#pragma unroll
    for (int k = 0; k < 8; ++k) {
        if (dd[k] >= 0) pos[k] = rowptr[dd[k]] + rk[k];
    }
#pragma unroll
    for (int k = 0; k < 8; ++k) {
        int e = base + k * 256;
        if (dd[k] >= 0) epair[pos[k]] = make_int2(e, ss[k]);
    }
}

// ================= node_fused: proven branchless body, er aliased into out_feat ====
// one wave per node; lane l owns dims 2l,2l+1; head hh = l>>4. CSR int2 epair.
// erout = out_feat region: er[n] is read by node n's own wave BEFORE it overwrites
// the same bytes (identical layout; proven safe r7-r9). EXP2 = raw v_exp_f32.
// Body shape is the proven form -- do NOT restructure.
#define DEGCAP 128

__global__ __launch_bounds__(256) void node_fused_kernel(
        const ushort* __restrict__ el_bf, float* __restrict__ erout,
        const int* __restrict__ rowptr, const int2* __restrict__ epair,
        const float* __restrict__ attn, float* __restrict__ out_a) {
    __shared__ float sp[4][DEGCAP * NH];   // 2 KB per wave

    const int wv = threadIdx.x >> 6;
    const int n = blockIdx.x * 4 + wv;
    if (n >= NNODES) return;
    const int lane = threadIdx.x & 63;
    const int hh = lane >> 4;
    const int lo = rowptr[n], hi = rowptr[n + 1];
    const int deg = hi - lo;
    float* spw = sp[wv];
    const int l2 = lane * 2;

    const float2 rv = *(const float2*)(erout + (size_t)n * HD + l2);
    const float a0 = attn[l2] * LOG2E, a1 = attn[l2 + 1] * LOG2E;

    float m = -3.4e38f, lsum = 0.0f, acc0 = 0.0f, acc1 = 0.0f;

    if (deg > 0 && deg <= DEGCAP) {
        // preload first chunk of up to 16 edge-source indices (coalesced, clamped)
        int jj0 = (lane & 15);
        if (jj0 >= deg) jj0 = deg - 1;
        int si = epair[lo + jj0].y;

        for (int base = 0; base < deg; base += 16) {
            // issue all gathers of this chunk (wave-uniform scalar base per edge)
            ushort2 u[16];
#pragma unroll
            for (int j = 0; j < 16; ++j) {
                if (base + j < deg) {
                    int s = __builtin_amdgcn_readlane(si, j);
                    u[j] = *(const ushort2*)(el_bf + (size_t)s * HD + l2);
                }
            }
            // prefetch next chunk's indices (hides index-load latency under compute)
            int si_nxt = si;
            if (base + 16 < deg) {
                int jj = base + 16 + (lane & 15);
                if (jj >= deg) jj = deg - 1;
                si_nxt = epair[lo + jj].y;
            }
            // process chunk: per-edge, branchless online softmax (proven shape)
#pragma unroll
            for (int j = 0; j < 16; ++j) {
                if (base + j < deg) {
                    float evx = bf2f(u[j].x), evy = bf2f(u[j].y);
                    float x0 = evx + rv.x; x0 = fmaxf(x0, NEG * x0);
                    float x1 = evy + rv.y; x1 = fmaxf(x1, NEG * x1);
                    float p = x0 * a0 + x1 * a1;        // log2-domain score
                    p += __shfl_xor(p, 1, 16);
                    p += __shfl_xor(p, 2, 16);
                    p += __shfl_xor(p, 4, 16);
                    p += __shfl_xor(p, 8, 16);
                    if ((lane & 15) == 0) spw[(base + j) * NH + hh] = p;
                    float mn = fmaxf(m, p);
                    float sc = EXP2(m - mn);
                    float w  = EXP2(p - mn);
                    lsum = lsum * sc + w;
                    acc0 = acc0 * sc + w * evx;
                    acc1 = acc1 * sc + w * evy;
                    m = mn;
                }
            }
            si = si_nxt;
        }
    } else if (deg > DEGCAP) {
        // fallback pass 1: online softmax only (no score stash)
        ushort2 u = {0,0};
        { int s_ = epair[lo].y; u = *(const ushort2*)(el_bf + (size_t)s_ * HD + l2); }
        for (int i = lo; i < hi; ++i) {
            float evx = bf2f(u.x), evy = bf2f(u.y);
            if (i + 1 < hi) { int s_ = epair[i + 1].y;
                u = *(const ushort2*)(el_bf + (size_t)s_ * HD + l2); }
            float x0 = evx + rv.x; x0 = fmaxf(x0, NEG * x0);
            float x1 = evy + rv.y; x1 = fmaxf(x1, NEG * x1);
            float p = x0 * a0 + x1 * a1;
            p += __shfl_xor(p, 1, 16);
            p += __shfl_xor(p, 2, 16);
            p += __shfl_xor(p, 4, 16);
            p += __shfl_xor(p, 8, 16);
            float mn = fmaxf(m, p);
            float sc = EXP2(m - mn);
            float w  = EXP2(p - mn);
            lsum = lsum * sc + w;
            acc0 = acc0 * sc + w * evx;
            acc1 = acc1 * sc + w * evy;
            m = mn;
        }
    }

    // write aggregated features (overwrites er[n] -- same bytes, own wave)
    float2 o;
    if (deg == 0) { o.x = 0.0f; o.y = 0.0f; }
    else { float inv = 1.0f / lsum; o.x = acc0 * inv; o.y = acc1 * inv; }
    *(float2*)(erout + (size_t)n * HD + l2) = o;

    if (deg == 0) return;

    // normalize + write attention weights
    float inv = 1.0f / lsum;
    if (deg <= DEGCAP) {
        // broadcast (m, inv) of head (lane&3) from its group (values uniform in group)
        float mh   = __shfl(m,   (lane & 3) << 4, 64);
        float invh = __shfl(inv, (lane & 3) << 4, 64);
        for (int q = (lane >> 2); q < deg; q += 16) {
            int e = epair[lo + q].x;
            float p = spw[q * NH + (lane & 3)];
            out_a[(size_t)e * NH + (lane & 3)] = EXP2(p - mh) * invh;
        }
    } else {
        // fallback pass 2: recompute scores and write a
        for (int i = lo; i < hi; ++i) {
            int s_ = epair[i].y;
            ushort2 u = *(const ushort2*)(el_bf + (size_t)s_ * HD + l2);
            float evx = bf2f(u.x), evy = bf2f(u.y);
            float x0 = evx + rv.x; x0 = fmaxf(x0, NEG * x0);
            float x1 = evy + rv.y; x1 = fmaxf(x1, NEG * x1);
            float p = x0 * a0 + x1 * a1;
            p += __shfl_xor(p, 1, 16);
            p += __shfl_xor(p, 2, 16);
            p += __shfl_xor(p, 4, 16);
            p += __shfl_xor(p, 8, 16);
            if ((lane & 15) == 0) {
                int e = epair[i].x;
                out_a[(size_t)e * NH + hh] = EXP2(p - m) * inv;
            }
        }
    }
}

extern "C" void kernel_launch(void* const* d_in, const int* in_sizes, int n_in,
                              void* d_out, int out_size, void* d_ws, size_t ws_size,
                              hipStream_t stream) {
    const float* h    = (const float*)d_in[0];
    const int*   src  = (const int*)d_in[1];
    const int*   dst  = (const int*)d_in[2];
    const float* Wsrc = (const float*)d_in[3];
    const float* bsrc = (const float*)d_in[4];
    const float* Wdst = (const float*)d_in[5];
    const float* bdst = (const float*)d_in[6];
    const float* attn = (const float*)d_in[7];

    float* out_feat = (float*)d_out;                       // N*128 (er aliased here)
    float* out_a    = out_feat + (size_t)NNODES * HD;      // E*4

    // workspace layout (16B-aligned chunks), ~23 MB total
    ushort* Wt       = (ushort*)d_ws;                        // 256*256 bf16 (128 KB)
    ushort* el_bf    = Wt + 2 * HD * INDIM;                  // N*128 bf16 (12.8 MB)
    int*    cnt_work = (int*)(el_bf + (size_t)NNODES * HD);  // N ints (200 KB)
    int*    rank     = cnt_work + NNODES;                    // E ints (3.2 MB)
    int2*   epair    = (int2*)(rank + NEDGES);               // E {eidx,esrc} (6.4 MB)
    int*    rowptr   = (int*)(epair + NEDGES);               // N+1
    int*    partials = rowptr + NNODES + 1;                  // SCAN_B

    // 1) fusedPre: clear cnt | W convert+transpose
    fusedPre_kernel<<<CLR_BLKS + CONVW_BLKS, 256, 0, stream>>>(
        cnt_work, Wsrc, Wdst, Wt);

    // 2) fusedG: MFMA GEMM 128x256 (el -> ws, er -> d_out) | rank-pass (ONE atomic pass)
    fusedG_kernel<<<GEMM_BLKS + RANK_BLKS, 256, 0, stream>>>(
        h, Wt, bsrc, bdst, el_bf, out_feat, dst, cnt_work, rank);

    // 3-4) 2-kernel scan chain -> rowptr
    scan_partial_kernel<<<SCAN_B, 256, 0, stream>>>(cnt_work, partials);
    scan_final_kernel<<<SCAN_B, 256, 0, stream>>>(cnt_work, partials, rowptr);

    // 5) scatter: NO atomics (pos = rowptr[dst] + rank)
    scatter_kernel<<<SCAT_BLKS, 256, 0, stream>>>(src, dst, rank, rowptr, epair);

    // 6) node_fused (erout = out_feat)
    node_fused_kernel<<<(NNODES + 3) / 4, 256, 0, stream>>>(
        el_bf, out_feat, rowptr, epair, attn, out_a);
}